// Round 22
// baseline (97.269 us; speedup 1.0000x reference)
//
#include <hip/hip_runtime.h>
#include <hip/hip_bf16.h>

// Problem constants (fixed by reference)
#define DIM      64
#define NCODE    1024
#define NROWS    131072          // 32*64*64
#define NTILES   64              // 1024 codes / 16 per MFMA tile
#define TAU      0.006f          // near-tie threshold (covers screen+mask error 4x)
#define TSTRIDE  4160            // packed tile: 64B hee + 4x1024B fragments

typedef __attribute__((ext_vector_type(8))) short  short8;  // 8 bf16 (4 VGPRs)
typedef __attribute__((ext_vector_type(4))) float  f32x4;

// Output layout (concatenated in reference return order, all f32):
#define DIFF_OFF 8388608
#define IND_OFF  8388609
#define NU_OFF   (8388609 + 131072)

// ws layout (float offsets)
#define WS_HEE      0            // 1024
#define WS_EMBEDT   1024         // 65536
#define WS_PARTIALS 66560        // 512
#define WS_RMSE     67072        // 131072 (per-row mse)
#define WS_COUNTER  198144       // 1 (int)
#define WS_FLAGLIST 198145       // 131072 (int)
#define WS_BPK      329220       // 66560 floats = 260 KiB packed codebook

__device__ __forceinline__ unsigned short bf16rn(float f) {
    unsigned int u = __float_as_uint(f);
    return (unsigned short)((u + 0x7FFFu + ((u >> 16) & 1u)) >> 16);
}
__device__ __forceinline__ float bf16tof(unsigned short h) {
    return __uint_as_float(((unsigned int)h) << 16);
}
__device__ __forceinline__ unsigned umin_(unsigned a, unsigned b) { return a < b ? a : b; }
__device__ __forceinline__ unsigned umax_(unsigned a, unsigned b) { return a > b ? a : b; }

// ---------------------------------------------------------------------------
// Fused prep (blocks 0..3) + codebook pack (blocks 4..35).
__global__ __launch_bounds__(256) void vq_prep(const float* __restrict__ embed,
                                               float* __restrict__ embedT,
                                               float* __restrict__ hee,
                                               int* __restrict__ counter,
                                               unsigned char* __restrict__ bpk) {
    if (blockIdx.x < 4) {
        int c = blockIdx.x * 256 + threadIdx.x;      // 0..1023
        if (c == 0) *counter = 0;
        float s = 0.f;
#pragma unroll
        for (int d = 0; d < DIM; ++d) {
            float v = embed[d * NCODE + c];
            embedT[c * DIM + d] = v;
            s = fmaf(v, v, s);
        }
        hee[c] = 0.5f * s;
    } else {
        int t  = (blockIdx.x - 4) * 256 + threadIdx.x;   // 0..8191
        int s  = t & 1;
        int l  = (t >> 1) & 63;
        int ct = t >> 7;
        int c  = ct * 16 + (l & 15);
        int kb = s * 32 + (l >> 4) * 8;

        unsigned int hw[4], lw[4];
#pragma unroll
        for (int w = 0; w < 4; ++w) {
            float v0 = embed[(kb + 2 * w)     * NCODE + c];
            float v1 = embed[(kb + 2 * w + 1) * NCODE + c];
            unsigned short h0 = bf16rn(v0), h1 = bf16rn(v1);
            unsigned short l0 = bf16rn(v0 - bf16tof(h0));
            unsigned short l1 = bf16rn(v1 - bf16tof(h1));
            hw[w] = (unsigned int)h0 | ((unsigned int)h1 << 16);
            lw[w] = (unsigned int)l0 | ((unsigned int)l1 << 16);
        }
        uint4* dst_h = (uint4*)(bpk + ct * TSTRIDE + 64 + s * 1024 + l * 16);
        uint4* dst_l = (uint4*)(bpk + ct * TSTRIDE + 64 + s * 1024 + l * 16 + 2048);
        *dst_h = make_uint4(hw[0], hw[1], hw[2], hw[3]);
        *dst_l = make_uint4(lw[0], lw[1], lw[2], lw[3]);
        if (s == 0 && l < 16) {
            float ss = 0.f;
#pragma unroll
            for (int d = 0; d < DIM; ++d) {
                float v = embed[d * NCODE + c];
                ss = fmaf(v, v, ss);
            }
            *(float*)(bpk + ct * TSTRIDE + l * 4) = 0.5f * ss;
        }
    }
}

// ---------------------------------------------------------------------------
// MFMA scoring v9: r17/r21 pipeline + SPLIT ACCUMULATOR CHAINS.
// r21 accounting: matrix 35% + VALU 47% = 82% issue; ~18% idle is exposed
// latency of the 6-deep dependent MFMA chain feeding each select. Split into
// two independent 3-chains (accA seeded with hh+hx, accB with 0; summed at
// select) -> 4 independent chains/tile, halving exposed latency. Rounding
// order changes slightly; any index that could flip is within the error
// bound << TAU -> flagged -> exactly rescored, so final indices are exact.
#define ISSUE_T(C0, C1, C2, C3, HH, FA, HA)                                   \
    asm volatile("global_load_dwordx4 %0, %1, off"             : "=v"(C0) : "v"(FA)); \
    asm volatile("global_load_dwordx4 %0, %1, off offset:1024" : "=v"(C1) : "v"(FA)); \
    asm volatile("global_load_dwordx4 %0, %1, off offset:2048" : "=v"(C2) : "v"(FA)); \
    asm volatile("global_load_dwordx4 %0, %1, off offset:3072" : "=v"(C3) : "v"(FA)); \
    asm volatile("global_load_dword %0, %1, off"               : "=v"(HH) : "v"(HA));

#define WAITN(N)                                                              \
    asm volatile("s_waitcnt vmcnt(" #N ")" ::: "memory");                     \
    __builtin_amdgcn_sched_barrier(0);

__global__ __launch_bounds__(256, 4) void vq_score_mfma(const float* __restrict__ input,
                                                        const unsigned char* __restrict__ bpk,
                                                        const float* __restrict__ embedT,
                                                        float* __restrict__ out_q,
                                                        float* __restrict__ out_ind,
                                                        float* __restrict__ row_mse,
                                                        int* __restrict__ counter,
                                                        int* __restrict__ flaglist) {
    const int tid   = threadIdx.x;
    const int wid   = tid >> 6;
    const int lane  = tid & 63;
    const int g     = lane >> 4;          // k-group / D-row group
    const int lc    = lane & 15;          // A-row within set / D-col (code)
    const int rbase = (blockIdx.x * 4 + wid) * 32;

    // Build A fragments (NEGATED x, hi+lo bf16) and per-slot hx = 0.5||x||^2+1.
    short8 ah[2][2], al[2][2];
    float  hx[2][4];
#pragma unroll
    for (int m = 0; m < 2; ++m) {
        float ssum = 0.f;
#pragma unroll
        for (int s = 0; s < 2; ++s) {
            const float* xr = input + (size_t)(rbase + m * 16 + lc) * DIM + s * 32 + g * 8;
            float4 f0 = *(const float4*)(xr);
            float4 f1 = *(const float4*)(xr + 4);
            float xf[8] = {f0.x, f0.y, f0.z, f0.w, f1.x, f1.y, f1.z, f1.w};
            short8 h8, l8;
#pragma unroll
            for (int j = 0; j < 8; ++j) {
                ssum = fmaf(xf[j], xf[j], ssum);
                float nx = -xf[j];
                unsigned short hb = bf16rn(nx);
                h8[j] = (short)hb;
                l8[j] = (short)bf16rn(nx - bf16tof(hb));
            }
            ah[m][s] = h8;
            al[m][s] = l8;
        }
        ssum += __shfl_xor(ssum, 16, 64);
        ssum += __shfl_xor(ssum, 32, 64);
#pragma unroll
        for (int j = 0; j < 4; ++j)
            hx[m][j] = 0.5f * __shfl(ssum, g * 4 + j, 64) + 1.0f;
    }

    unsigned m1[8], m2[8];
#pragma unroll
    for (int t = 0; t < 8; ++t) { m1[t] = 0xFFFFFFFFu; m2[t] = 0xFFFFFFFFu; }

#define COMPT(T, C0, C1, C2, C3, HH)                                          \
    {   short8 s0 = __builtin_bit_cast(short8, C0);                           \
        short8 s1 = __builtin_bit_cast(short8, C1);                           \
        short8 s2 = __builtin_bit_cast(short8, C2);                           \
        short8 s3 = __builtin_bit_cast(short8, C3);                           \
        _Pragma("unroll")                                                     \
        for (int m = 0; m < 2; ++m) {                                         \
            f32x4 accA = {(HH) + hx[m][0], (HH) + hx[m][1],                   \
                          (HH) + hx[m][2], (HH) + hx[m][3]};                  \
            f32x4 accB = {0.f, 0.f, 0.f, 0.f};                                \
            __builtin_amdgcn_s_setprio(1);                                    \
            accA = __builtin_amdgcn_mfma_f32_16x16x32_bf16(ah[m][0], s0, accA, 0, 0, 0); \
            accB = __builtin_amdgcn_mfma_f32_16x16x32_bf16(al[m][0], s0, accB, 0, 0, 0); \
            accA = __builtin_amdgcn_mfma_f32_16x16x32_bf16(ah[m][0], s2, accA, 0, 0, 0); \
            accB = __builtin_amdgcn_mfma_f32_16x16x32_bf16(ah[m][1], s1, accB, 0, 0, 0); \
            accA = __builtin_amdgcn_mfma_f32_16x16x32_bf16(al[m][1], s1, accA, 0, 0, 0); \
            accB = __builtin_amdgcn_mfma_f32_16x16x32_bf16(ah[m][1], s3, accB, 0, 0, 0); \
            __builtin_amdgcn_s_setprio(0);                                    \
            _Pragma("unroll")                                                 \
            for (int j = 0; j < 4; ++j) {                                     \
                unsigned bits = __float_as_uint(accA[j] + accB[j]);           \
                unsigned pk   = (bits & 0xFFFFFFC0u) | (unsigned)(T);         \
                int s = m * 4 + j;                                            \
                m2[s] = umin_(m2[s], umax_(pk, m1[s]));                       \
                m1[s] = umin_(m1[s], pk);                                     \
            }                                                                 \
        } }

    // Address registers, stepped by 2*TSTRIDE per buffer.
    unsigned long long fA = (unsigned long long)(uintptr_t)(bpk + 64 + lane * 16);
    unsigned long long hA = (unsigned long long)(uintptr_t)(bpk + lc * 4);
    unsigned long long fB = fA + TSTRIDE;
    unsigned long long hB = hA + TSTRIDE;

    uint4 a0, a1, a2, a3;  float ahh;   // ping (even tiles)
    uint4 b0, b1, b2, b3;  float bhh;   // pong (odd tiles)

    ISSUE_T(a0, a1, a2, a3, ahh, fA, hA);            // tile 0 in flight
    fA += 2 * TSTRIDE;  hA += 2 * TSTRIDE;

    for (int ct = 0; ct < NTILES - 2; ct += 2) {
        ISSUE_T(b0, b1, b2, b3, bhh, fB, hB);        // tile ct+1 in flight
        fB += 2 * TSTRIDE;  hB += 2 * TSTRIDE;
        WAITN(5);                                    // tile ct ready; ct+1 in flight
        COMPT(ct, a0, a1, a2, a3, ahh);
        ISSUE_T(a0, a1, a2, a3, ahh, fA, hA);        // tile ct+2 in flight
        fA += 2 * TSTRIDE;  hA += 2 * TSTRIDE;
        WAITN(5);                                    // tile ct+1 ready
        COMPT(ct + 1, b0, b1, b2, b3, bhh);
    }
    // Tail: tiles 62 (in flight in A) and 63.
    ISSUE_T(b0, b1, b2, b3, bhh, fB, hB);
    WAITN(5);
    COMPT(NTILES - 2, a0, a1, a2, a3, ahh);
    WAITN(0);
    COMPT(NTILES - 1, b0, b1, b2, b3, bhh);

#undef COMPT

    // Merge + fused coalesced epilogue (r17, measured).
#pragma unroll
    for (int m = 0; m < 2; ++m) {
#pragma unroll
        for (int j = 0; j < 4; ++j) {
            int s = m * 4 + j;
            unsigned v1 = m1[s], v2 = m2[s];
            int ii = (int)(((v1 & 63u) << 4) | (unsigned)lc);   // full code
#pragma unroll
            for (int d = 1; d < 16; d <<= 1) {
                unsigned o1 = __shfl_xor(v1, d, 64);
                int      oi = __shfl_xor(ii, d, 64);
                unsigned o2 = __shfl_xor(v2, d, 64);
                bool sw = (o1 < v1) || (o1 == v1 && oi < ii);
                unsigned losing = sw ? v1 : o1;
                v2 = umin_(umin_(v2, o2), losing);
                v1 = sw ? o1 : v1;
                ii = sw ? oi : ii;
            }
            int row = rbase + m * 16 + g * 4 + j;    // per-lane (g varies)
            ((float4*)(out_q + (size_t)row * DIM))[lc] =
                ((const float4*)(embedT + (size_t)ii * DIM))[lc];
            if (lc == 0) {
                out_ind[row] = (float)ii;
                row_mse[row] = 2.0f * (__uint_as_float(v1 & 0xFFFFFFC0u) - 1.0f);
                float gap = __uint_as_float(v2 & 0xFFFFFFC0u)
                          - __uint_as_float(v1 & 0xFFFFFFC0u);
                if (gap < TAU) {
                    int p = atomicAdd(counter, 1);
                    flaglist[p] = row;
                }
            }
        }
    }
}

// ---------------------------------------------------------------------------
// Exact rescore, 2 flagged rows per embedT sweep; rewrites quantize rows,
// ind, and exact row_mse (= ||x||^2 - 2*s_best) in place.
__global__ __launch_bounds__(64) void vq_rescore(const float* __restrict__ input,
                                                 const float* __restrict__ embedT,
                                                 const float* __restrict__ hee,
                                                 const int* __restrict__ counter,
                                                 const int* __restrict__ flaglist,
                                                 float* __restrict__ out_q,
                                                 float* __restrict__ out_ind,
                                                 float* __restrict__ row_mse) {
    const int lane = threadIdx.x;
    const int cnt  = *counter;
    for (int i = blockIdx.x * 2; i < cnt; i += gridDim.x * 2) {
        const int r0 = flaglist[i];
        const int r1 = (i + 1 < cnt) ? flaglist[i + 1] : r0;
        float4 xa[16], xb[16];
        float ssA = 0.f, ssB = 0.f;
        {
            const float4* pa = (const float4*)(input + (size_t)r0 * DIM);
            const float4* pb = (const float4*)(input + (size_t)r1 * DIM);
#pragma unroll
            for (int k = 0; k < 16; ++k) {
                xa[k] = pa[k]; xb[k] = pb[k];
                ssA = fmaf(xa[k].x, xa[k].x, ssA); ssA = fmaf(xa[k].y, xa[k].y, ssA);
                ssA = fmaf(xa[k].z, xa[k].z, ssA); ssA = fmaf(xa[k].w, xa[k].w, ssA);
                ssB = fmaf(xb[k].x, xb[k].x, ssB); ssB = fmaf(xb[k].y, xb[k].y, ssB);
                ssB = fmaf(xb[k].z, xb[k].z, ssB); ssB = fmaf(xb[k].w, xb[k].w, ssB);
            }
        }
        float bestA = -3.402823466e+38f, bestB = -3.402823466e+38f;
        int   biA = 0, biB = 0;
#pragma unroll 1
        for (int k = 0; k < 16; ++k) {
            int c = lane * 16 + k;
            const float4* e4 = (const float4*)(embedT + (size_t)c * DIM);
            float hh = hee[c];
            float a0 = -hh, a1 = 0.f, a2 = 0.f, a3 = 0.f;
            float b0 = -hh, b1 = 0.f, b2 = 0.f, b3 = 0.f;
#pragma unroll
            for (int q = 0; q < 4; ++q) {
                float4 e0 = e4[4 * q + 0], e1 = e4[4 * q + 1];
                float4 e2 = e4[4 * q + 2], e3 = e4[4 * q + 3];
                float4 p0 = xa[4 * q + 0], p1 = xa[4 * q + 1];
                float4 p2 = xa[4 * q + 2], p3 = xa[4 * q + 3];
                float4 q0 = xb[4 * q + 0], q1 = xb[4 * q + 1];
                float4 q2 = xb[4 * q + 2], q3 = xb[4 * q + 3];
                a0 = fmaf(e0.x, p0.x, a0); a0 = fmaf(e0.y, p0.y, a0);
                a0 = fmaf(e0.z, p0.z, a0); a0 = fmaf(e0.w, p0.w, a0);
                a1 = fmaf(e1.x, p1.x, a1); a1 = fmaf(e1.y, p1.y, a1);
                a1 = fmaf(e1.z, p1.z, a1); a1 = fmaf(e1.w, p1.w, a1);
                a2 = fmaf(e2.x, p2.x, a2); a2 = fmaf(e2.y, p2.y, a2);
                a2 = fmaf(e2.z, p2.z, a2); a2 = fmaf(e2.w, p2.w, a2);
                a3 = fmaf(e3.x, p3.x, a3); a3 = fmaf(e3.y, p3.y, a3);
                a3 = fmaf(e3.z, p3.z, a3); a3 = fmaf(e3.w, p3.w, a3);
                b0 = fmaf(e0.x, q0.x, b0); b0 = fmaf(e0.y, q0.y, b0);
                b0 = fmaf(e0.z, q0.z, b0); b0 = fmaf(e0.w, q0.w, b0);
                b1 = fmaf(e1.x, q1.x, b1); b1 = fmaf(e1.y, q1.y, b1);
                b1 = fmaf(e1.z, q1.z, b1); b1 = fmaf(e1.w, q1.w, b1);
                b2 = fmaf(e2.x, q2.x, b2); b2 = fmaf(e2.y, q2.y, b2);
                b2 = fmaf(e2.z, q2.z, b2); b2 = fmaf(e2.w, q2.w, b2);
                b3 = fmaf(e3.x, q3.x, b3); b3 = fmaf(e3.y, q3.y, b3);
                b3 = fmaf(e3.z, q3.z, b3); b3 = fmaf(e3.w, q3.w, b3);
            }
            float sA = (a0 + a1) + (a2 + a3);
            float sB = (b0 + b1) + (b2 + b3);
            if (sA > bestA) { bestA = sA; biA = c; }
            if (sB > bestB) { bestB = sB; biB = c; }
        }
#pragma unroll
        for (int d = 1; d < 64; d <<= 1) {
            float oA = __shfl_xor(bestA, d, 64);
            int   iA = __shfl_xor(biA, d, 64);
            bool  sA = (oA > bestA) || (oA == bestA && iA < biA);
            bestA = sA ? oA : bestA;
            biA   = sA ? iA : biA;
            float oB = __shfl_xor(bestB, d, 64);
            int   iB = __shfl_xor(biB, d, 64);
            bool  sB = (oB > bestB) || (oB == bestB && iB < biB);
            bestB = sB ? oB : bestB;
            biB   = sB ? iB : biB;
        }
        if (lane == 0) {
            out_ind[r0] = (float)biA;
            row_mse[r0] = ssA - 2.0f * bestA;
            out_ind[r1] = (float)biB;
            row_mse[r1] = ssB - 2.0f * bestB;
        }
        {
            int half = lane >> 4;
            int fi   = lane & 15;
            if (half == 0) {
                ((float4*)(out_q + (size_t)r0 * DIM))[fi] =
                    ((const float4*)(embedT + (size_t)biA * DIM))[fi];
            } else if (half == 1) {
                ((float4*)(out_q + (size_t)r1 * DIM))[fi] =
                    ((const float4*)(embedT + (size_t)biB * DIM))[fi];
            }
        }
    }
}

// ---------------------------------------------------------------------------
// Deterministic reduction of row_mse -> 512 block partials (fixed order).
__global__ __launch_bounds__(256) void vq_mse_reduce(const float* __restrict__ row_mse,
                                                     float* __restrict__ partials) {
    __shared__ float wsum[4];
    const int tid = threadIdx.x;
    float acc = row_mse[blockIdx.x * 256 + tid];
#pragma unroll
    for (int off = 32; off > 0; off >>= 1) acc += __shfl_down(acc, off, 64);
    if ((tid & 63) == 0) wsum[tid >> 6] = acc;
    __syncthreads();
    if (tid == 0) partials[blockIdx.x] = (wsum[0] + wsum[1]) + (wsum[2] + wsum[3]);
}

// ---------------------------------------------------------------------------
__global__ __launch_bounds__(256) void vq_finalize(const float* __restrict__ partials,
                                                   float* __restrict__ out,
                                                   int out_size) {
    __shared__ float sm[256];
    int t = threadIdx.x;
    float v = partials[t] + partials[t + 256];
    sm[t] = v;
    __syncthreads();
    for (int s = 128; s > 0; s >>= 1) {
        if (t < s) sm[t] += sm[t + s];
        __syncthreads();
    }
    if (t == 0) out[DIFF_OFF] = sm[0] / 8388608.0f;
    if (t == 1 && out_size > NU_OFF) out[NU_OFF] = -1.0f;
}

// ---------------------------------------------------------------------------
extern "C" void kernel_launch(void* const* d_in, const int* in_sizes, int n_in,
                              void* d_out, int out_size, void* d_ws, size_t ws_size,
                              hipStream_t stream) {
    const float* input = (const float*)d_in[0];   // [32,64,64,64]
    const float* embed = (const float*)d_in[1];   // [64,1024]
    float* out = (float*)d_out;
    float* ws  = (float*)d_ws;

    float* hee      = ws + WS_HEE;
    float* embedT   = ws + WS_EMBEDT;
    float* partials = ws + WS_PARTIALS;
    float* row_mse  = ws + WS_RMSE;
    int*   counter  = (int*)(ws + WS_COUNTER);
    int*   flaglist = (int*)(ws + WS_FLAGLIST);
    unsigned char* bpk = (unsigned char*)(ws + WS_BPK);

    vq_prep<<<36, 256, 0, stream>>>(embed, embedT, hee, counter, bpk);
    vq_score_mfma<<<1024, 256, 0, stream>>>(input, bpk, embedT,
                                            out, out + IND_OFF, row_mse,
                                            counter, flaglist);
    vq_rescore<<<2048, 64, 0, stream>>>(input, embedT, hee, counter, flaglist,
                                        out, out + IND_OFF, row_mse);
    vq_mse_reduce<<<512, 256, 0, stream>>>(row_mse, partials);
    vq_finalize<<<1, 256, 0, stream>>>(partials, out, out_size);
}

// Round 23
// 91.334 us; speedup vs baseline: 1.0650x; 1.0650x over previous
//
#include <hip/hip_runtime.h>
#include <hip/hip_bf16.h>

// Problem constants (fixed by reference)
#define DIM      64
#define NCODE    1024
#define NROWS    131072          // 32*64*64
#define NTILES   64              // 1024 codes / 16 per MFMA tile
#define TAU      0.006f          // near-tie threshold (covers screen+mask error 4x)
#define TSTRIDE  4160            // packed tile: 64B hee + 4x1024B fragments

typedef __attribute__((ext_vector_type(8))) short  short8;  // 8 bf16 (4 VGPRs)
typedef __attribute__((ext_vector_type(4))) float  f32x4;

// Output layout (concatenated in reference return order, all f32):
#define DIFF_OFF 8388608
#define IND_OFF  8388609
#define NU_OFF   (8388609 + 131072)

// ws layout (float offsets)
#define WS_HEE      0            // 1024
#define WS_EMBEDT   1024         // 65536
#define WS_PARTIALS 66560        // 512
#define WS_RMSE     67072        // 131072 (per-row mse)
#define WS_COUNTER  198144       // 1 (int)
#define WS_FLAGLIST 198145       // 131072 (int)
#define WS_BPK      329220       // 66560 floats = 260 KiB packed codebook

__device__ __forceinline__ unsigned short bf16rn(float f) {
    unsigned int u = __float_as_uint(f);
    return (unsigned short)((u + 0x7FFFu + ((u >> 16) & 1u)) >> 16);
}
__device__ __forceinline__ float bf16tof(unsigned short h) {
    return __uint_as_float(((unsigned int)h) << 16);
}
__device__ __forceinline__ unsigned umin_(unsigned a, unsigned b) { return a < b ? a : b; }
__device__ __forceinline__ unsigned umax_(unsigned a, unsigned b) { return a > b ? a : b; }

// ---------------------------------------------------------------------------
// Fused prep (blocks 0..3) + codebook pack (blocks 4..35).
__global__ __launch_bounds__(256) void vq_prep(const float* __restrict__ embed,
                                               float* __restrict__ embedT,
                                               float* __restrict__ hee,
                                               int* __restrict__ counter,
                                               unsigned char* __restrict__ bpk) {
    if (blockIdx.x < 4) {
        int c = blockIdx.x * 256 + threadIdx.x;      // 0..1023
        if (c == 0) *counter = 0;
        float s = 0.f;
#pragma unroll
        for (int d = 0; d < DIM; ++d) {
            float v = embed[d * NCODE + c];
            embedT[c * DIM + d] = v;
            s = fmaf(v, v, s);
        }
        hee[c] = 0.5f * s;
    } else {
        int t  = (blockIdx.x - 4) * 256 + threadIdx.x;   // 0..8191
        int s  = t & 1;
        int l  = (t >> 1) & 63;
        int ct = t >> 7;
        int c  = ct * 16 + (l & 15);
        int kb = s * 32 + (l >> 4) * 8;

        unsigned int hw[4], lw[4];
#pragma unroll
        for (int w = 0; w < 4; ++w) {
            float v0 = embed[(kb + 2 * w)     * NCODE + c];
            float v1 = embed[(kb + 2 * w + 1) * NCODE + c];
            unsigned short h0 = bf16rn(v0), h1 = bf16rn(v1);
            unsigned short l0 = bf16rn(v0 - bf16tof(h0));
            unsigned short l1 = bf16rn(v1 - bf16tof(h1));
            hw[w] = (unsigned int)h0 | ((unsigned int)h1 << 16);
            lw[w] = (unsigned int)l0 | ((unsigned int)l1 << 16);
        }
        uint4* dst_h = (uint4*)(bpk + ct * TSTRIDE + 64 + s * 1024 + l * 16);
        uint4* dst_l = (uint4*)(bpk + ct * TSTRIDE + 64 + s * 1024 + l * 16 + 2048);
        *dst_h = make_uint4(hw[0], hw[1], hw[2], hw[3]);
        *dst_l = make_uint4(lw[0], lw[1], lw[2], lw[3]);
        if (s == 0 && l < 16) {
            float ss = 0.f;
#pragma unroll
            for (int d = 0; d < DIM; ++d) {
                float v = embed[d * NCODE + c];
                ss = fmaf(v, v, ss);
            }
            *(float*)(bpk + ct * TSTRIDE + l * 4) = 0.5f * ss;
        }
    }
}

// ---------------------------------------------------------------------------
// MFMA scoring v8 (r17/r21, measured 61-64us twice): counted-vmcnt pipeline
// + coalesced barrier-free fused epilogue. Six structural variants measured
// against this loop (occupancy, LDS staging, reg dbuf, counted vmcnt,
// setprio, split chains) -> this is the plateau configuration.
#define ISSUE_T(C0, C1, C2, C3, HH, FA, HA)                                   \
    asm volatile("global_load_dwordx4 %0, %1, off"             : "=v"(C0) : "v"(FA)); \
    asm volatile("global_load_dwordx4 %0, %1, off offset:1024" : "=v"(C1) : "v"(FA)); \
    asm volatile("global_load_dwordx4 %0, %1, off offset:2048" : "=v"(C2) : "v"(FA)); \
    asm volatile("global_load_dwordx4 %0, %1, off offset:3072" : "=v"(C3) : "v"(FA)); \
    asm volatile("global_load_dword %0, %1, off"               : "=v"(HH) : "v"(HA));

#define WAITN(N)                                                              \
    asm volatile("s_waitcnt vmcnt(" #N ")" ::: "memory");                     \
    __builtin_amdgcn_sched_barrier(0);

__global__ __launch_bounds__(256, 4) void vq_score_mfma(const float* __restrict__ input,
                                                        const unsigned char* __restrict__ bpk,
                                                        const float* __restrict__ embedT,
                                                        float* __restrict__ out_q,
                                                        float* __restrict__ out_ind,
                                                        float* __restrict__ row_mse,
                                                        int* __restrict__ counter,
                                                        int* __restrict__ flaglist) {
    const int tid   = threadIdx.x;
    const int wid   = tid >> 6;
    const int lane  = tid & 63;
    const int g     = lane >> 4;          // k-group / D-row group
    const int lc    = lane & 15;          // A-row within set / D-col (code)
    const int rbase = (blockIdx.x * 4 + wid) * 32;

    // Build A fragments (NEGATED x, hi+lo bf16) and per-slot hx = 0.5||x||^2+1.
    short8 ah[2][2], al[2][2];
    float  hx[2][4];
#pragma unroll
    for (int m = 0; m < 2; ++m) {
        float ssum = 0.f;
#pragma unroll
        for (int s = 0; s < 2; ++s) {
            const float* xr = input + (size_t)(rbase + m * 16 + lc) * DIM + s * 32 + g * 8;
            float4 f0 = *(const float4*)(xr);
            float4 f1 = *(const float4*)(xr + 4);
            float xf[8] = {f0.x, f0.y, f0.z, f0.w, f1.x, f1.y, f1.z, f1.w};
            short8 h8, l8;
#pragma unroll
            for (int j = 0; j < 8; ++j) {
                ssum = fmaf(xf[j], xf[j], ssum);
                float nx = -xf[j];
                unsigned short hb = bf16rn(nx);
                h8[j] = (short)hb;
                l8[j] = (short)bf16rn(nx - bf16tof(hb));
            }
            ah[m][s] = h8;
            al[m][s] = l8;
        }
        ssum += __shfl_xor(ssum, 16, 64);
        ssum += __shfl_xor(ssum, 32, 64);
#pragma unroll
        for (int j = 0; j < 4; ++j)
            hx[m][j] = 0.5f * __shfl(ssum, g * 4 + j, 64) + 1.0f;
    }

    unsigned m1[8], m2[8];
#pragma unroll
    for (int t = 0; t < 8; ++t) { m1[t] = 0xFFFFFFFFu; m2[t] = 0xFFFFFFFFu; }

#define COMPT(T, C0, C1, C2, C3, HH)                                          \
    {   short8 s0 = __builtin_bit_cast(short8, C0);                           \
        short8 s1 = __builtin_bit_cast(short8, C1);                           \
        short8 s2 = __builtin_bit_cast(short8, C2);                           \
        short8 s3 = __builtin_bit_cast(short8, C3);                           \
        _Pragma("unroll")                                                     \
        for (int m = 0; m < 2; ++m) {                                         \
            f32x4 acc = {(HH) + hx[m][0], (HH) + hx[m][1],                    \
                         (HH) + hx[m][2], (HH) + hx[m][3]};                   \
            __builtin_amdgcn_s_setprio(1);                                    \
            acc = __builtin_amdgcn_mfma_f32_16x16x32_bf16(ah[m][0], s0, acc, 0, 0, 0); \
            acc = __builtin_amdgcn_mfma_f32_16x16x32_bf16(al[m][0], s0, acc, 0, 0, 0); \
            acc = __builtin_amdgcn_mfma_f32_16x16x32_bf16(ah[m][0], s2, acc, 0, 0, 0); \
            acc = __builtin_amdgcn_mfma_f32_16x16x32_bf16(ah[m][1], s1, acc, 0, 0, 0); \
            acc = __builtin_amdgcn_mfma_f32_16x16x32_bf16(al[m][1], s1, acc, 0, 0, 0); \
            acc = __builtin_amdgcn_mfma_f32_16x16x32_bf16(ah[m][1], s3, acc, 0, 0, 0); \
            __builtin_amdgcn_s_setprio(0);                                    \
            _Pragma("unroll")                                                 \
            for (int j = 0; j < 4; ++j) {                                     \
                unsigned bits = __float_as_uint(acc[j]);                      \
                unsigned pk   = (bits & 0xFFFFFFC0u) | (unsigned)(T);         \
                int s = m * 4 + j;                                            \
                m2[s] = umin_(m2[s], umax_(pk, m1[s]));                       \
                m1[s] = umin_(m1[s], pk);                                     \
            }                                                                 \
        } }

    // Address registers, stepped by 2*TSTRIDE per buffer.
    unsigned long long fA = (unsigned long long)(uintptr_t)(bpk + 64 + lane * 16);
    unsigned long long hA = (unsigned long long)(uintptr_t)(bpk + lc * 4);
    unsigned long long fB = fA + TSTRIDE;
    unsigned long long hB = hA + TSTRIDE;

    uint4 a0, a1, a2, a3;  float ahh;   // ping (even tiles)
    uint4 b0, b1, b2, b3;  float bhh;   // pong (odd tiles)

    ISSUE_T(a0, a1, a2, a3, ahh, fA, hA);            // tile 0 in flight
    fA += 2 * TSTRIDE;  hA += 2 * TSTRIDE;

    for (int ct = 0; ct < NTILES - 2; ct += 2) {
        ISSUE_T(b0, b1, b2, b3, bhh, fB, hB);        // tile ct+1 in flight
        fB += 2 * TSTRIDE;  hB += 2 * TSTRIDE;
        WAITN(5);                                    // tile ct ready; ct+1 in flight
        COMPT(ct, a0, a1, a2, a3, ahh);
        ISSUE_T(a0, a1, a2, a3, ahh, fA, hA);        // tile ct+2 in flight
        fA += 2 * TSTRIDE;  hA += 2 * TSTRIDE;
        WAITN(5);                                    // tile ct+1 ready
        COMPT(ct + 1, b0, b1, b2, b3, bhh);
    }
    // Tail: tiles 62 (in flight in A) and 63.
    ISSUE_T(b0, b1, b2, b3, bhh, fB, hB);
    WAITN(5);
    COMPT(NTILES - 2, a0, a1, a2, a3, ahh);
    WAITN(0);
    COMPT(NTILES - 1, b0, b1, b2, b3, bhh);

#undef COMPT

    // Merge + fused coalesced epilogue (r17, measured).
#pragma unroll
    for (int m = 0; m < 2; ++m) {
#pragma unroll
        for (int j = 0; j < 4; ++j) {
            int s = m * 4 + j;
            unsigned v1 = m1[s], v2 = m2[s];
            int ii = (int)(((v1 & 63u) << 4) | (unsigned)lc);   // full code
#pragma unroll
            for (int d = 1; d < 16; d <<= 1) {
                unsigned o1 = __shfl_xor(v1, d, 64);
                int      oi = __shfl_xor(ii, d, 64);
                unsigned o2 = __shfl_xor(v2, d, 64);
                bool sw = (o1 < v1) || (o1 == v1 && oi < ii);
                unsigned losing = sw ? v1 : o1;
                v2 = umin_(umin_(v2, o2), losing);
                v1 = sw ? o1 : v1;
                ii = sw ? oi : ii;
            }
            int row = rbase + m * 16 + g * 4 + j;    // per-lane (g varies)
            ((float4*)(out_q + (size_t)row * DIM))[lc] =
                ((const float4*)(embedT + (size_t)ii * DIM))[lc];
            if (lc == 0) {
                out_ind[row] = (float)ii;
                row_mse[row] = 2.0f * (__uint_as_float(v1 & 0xFFFFFFC0u) - 1.0f);
                float gap = __uint_as_float(v2 & 0xFFFFFFC0u)
                          - __uint_as_float(v1 & 0xFFFFFFC0u);
                if (gap < TAU) {
                    int p = atomicAdd(counter, 1);
                    flaglist[p] = row;
                }
            }
        }
    }
}

// ---------------------------------------------------------------------------
// Exact rescore, 2 flagged rows per embedT sweep; rewrites quantize rows,
// ind, and exact row_mse (= ||x||^2 - 2*s_best) in place.
__global__ __launch_bounds__(64) void vq_rescore(const float* __restrict__ input,
                                                 const float* __restrict__ embedT,
                                                 const float* __restrict__ hee,
                                                 const int* __restrict__ counter,
                                                 const int* __restrict__ flaglist,
                                                 float* __restrict__ out_q,
                                                 float* __restrict__ out_ind,
                                                 float* __restrict__ row_mse) {
    const int lane = threadIdx.x;
    const int cnt  = *counter;
    for (int i = blockIdx.x * 2; i < cnt; i += gridDim.x * 2) {
        const int r0 = flaglist[i];
        const int r1 = (i + 1 < cnt) ? flaglist[i + 1] : r0;
        float4 xa[16], xb[16];
        float ssA = 0.f, ssB = 0.f;
        {
            const float4* pa = (const float4*)(input + (size_t)r0 * DIM);
            const float4* pb = (const float4*)(input + (size_t)r1 * DIM);
#pragma unroll
            for (int k = 0; k < 16; ++k) {
                xa[k] = pa[k]; xb[k] = pb[k];
                ssA = fmaf(xa[k].x, xa[k].x, ssA); ssA = fmaf(xa[k].y, xa[k].y, ssA);
                ssA = fmaf(xa[k].z, xa[k].z, ssA); ssA = fmaf(xa[k].w, xa[k].w, ssA);
                ssB = fmaf(xb[k].x, xb[k].x, ssB); ssB = fmaf(xb[k].y, xb[k].y, ssB);
                ssB = fmaf(xb[k].z, xb[k].z, ssB); ssB = fmaf(xb[k].w, xb[k].w, ssB);
            }
        }
        float bestA = -3.402823466e+38f, bestB = -3.402823466e+38f;
        int   biA = 0, biB = 0;
#pragma unroll 1
        for (int k = 0; k < 16; ++k) {
            int c = lane * 16 + k;
            const float4* e4 = (const float4*)(embedT + (size_t)c * DIM);
            float hh = hee[c];
            float a0 = -hh, a1 = 0.f, a2 = 0.f, a3 = 0.f;
            float b0 = -hh, b1 = 0.f, b2 = 0.f, b3 = 0.f;
#pragma unroll
            for (int q = 0; q < 4; ++q) {
                float4 e0 = e4[4 * q + 0], e1 = e4[4 * q + 1];
                float4 e2 = e4[4 * q + 2], e3 = e4[4 * q + 3];
                float4 p0 = xa[4 * q + 0], p1 = xa[4 * q + 1];
                float4 p2 = xa[4 * q + 2], p3 = xa[4 * q + 3];
                float4 q0 = xb[4 * q + 0], q1 = xb[4 * q + 1];
                float4 q2 = xb[4 * q + 2], q3 = xb[4 * q + 3];
                a0 = fmaf(e0.x, p0.x, a0); a0 = fmaf(e0.y, p0.y, a0);
                a0 = fmaf(e0.z, p0.z, a0); a0 = fmaf(e0.w, p0.w, a0);
                a1 = fmaf(e1.x, p1.x, a1); a1 = fmaf(e1.y, p1.y, a1);
                a1 = fmaf(e1.z, p1.z, a1); a1 = fmaf(e1.w, p1.w, a1);
                a2 = fmaf(e2.x, p2.x, a2); a2 = fmaf(e2.y, p2.y, a2);
                a2 = fmaf(e2.z, p2.z, a2); a2 = fmaf(e2.w, p2.w, a2);
                a3 = fmaf(e3.x, p3.x, a3); a3 = fmaf(e3.y, p3.y, a3);
                a3 = fmaf(e3.z, p3.z, a3); a3 = fmaf(e3.w, p3.w, a3);
                b0 = fmaf(e0.x, q0.x, b0); b0 = fmaf(e0.y, q0.y, b0);
                b0 = fmaf(e0.z, q0.z, b0); b0 = fmaf(e0.w, q0.w, b0);
                b1 = fmaf(e1.x, q1.x, b1); b1 = fmaf(e1.y, q1.y, b1);
                b1 = fmaf(e1.z, q1.z, b1); b1 = fmaf(e1.w, q1.w, b1);
                b2 = fmaf(e2.x, q2.x, b2); b2 = fmaf(e2.y, q2.y, b2);
                b2 = fmaf(e2.z, q2.z, b2); b2 = fmaf(e2.w, q2.w, b2);
                b3 = fmaf(e3.x, q3.x, b3); b3 = fmaf(e3.y, q3.y, b3);
                b3 = fmaf(e3.z, q3.z, b3); b3 = fmaf(e3.w, q3.w, b3);
            }
            float sA = (a0 + a1) + (a2 + a3);
            float sB = (b0 + b1) + (b2 + b3);
            if (sA > bestA) { bestA = sA; biA = c; }
            if (sB > bestB) { bestB = sB; biB = c; }
        }
#pragma unroll
        for (int d = 1; d < 64; d <<= 1) {
            float oA = __shfl_xor(bestA, d, 64);
            int   iA = __shfl_xor(biA, d, 64);
            bool  sA = (oA > bestA) || (oA == bestA && iA < biA);
            bestA = sA ? oA : bestA;
            biA   = sA ? iA : biA;
            float oB = __shfl_xor(bestB, d, 64);
            int   iB = __shfl_xor(biB, d, 64);
            bool  sB = (oB > bestB) || (oB == bestB && iB < biB);
            bestB = sB ? oB : bestB;
            biB   = sB ? iB : biB;
        }
        if (lane == 0) {
            out_ind[r0] = (float)biA;
            row_mse[r0] = ssA - 2.0f * bestA;
            out_ind[r1] = (float)biB;
            row_mse[r1] = ssB - 2.0f * bestB;
        }
        {
            int half = lane >> 4;
            int fi   = lane & 15;
            if (half == 0) {
                ((float4*)(out_q + (size_t)r0 * DIM))[fi] =
                    ((const float4*)(embedT + (size_t)biA * DIM))[fi];
            } else if (half == 1) {
                ((float4*)(out_q + (size_t)r1 * DIM))[fi] =
                    ((const float4*)(embedT + (size_t)biB * DIM))[fi];
            }
        }
    }
}

// ---------------------------------------------------------------------------
// Deterministic reduction of row_mse -> 512 block partials (fixed order).
__global__ __launch_bounds__(256) void vq_mse_reduce(const float* __restrict__ row_mse,
                                                     float* __restrict__ partials) {
    __shared__ float wsum[4];
    const int tid = threadIdx.x;
    float acc = row_mse[blockIdx.x * 256 + tid];
#pragma unroll
    for (int off = 32; off > 0; off >>= 1) acc += __shfl_down(acc, off, 64);
    if ((tid & 63) == 0) wsum[tid >> 6] = acc;
    __syncthreads();
    if (tid == 0) partials[blockIdx.x] = (wsum[0] + wsum[1]) + (wsum[2] + wsum[3]);
}

// ---------------------------------------------------------------------------
__global__ __launch_bounds__(256) void vq_finalize(const float* __restrict__ partials,
                                                   float* __restrict__ out,
                                                   int out_size) {
    __shared__ float sm[256];
    int t = threadIdx.x;
    float v = partials[t] + partials[t + 256];
    sm[t] = v;
    __syncthreads();
    for (int s = 128; s > 0; s >>= 1) {
        if (t < s) sm[t] += sm[t + s];
        __syncthreads();
    }
    if (t == 0) out[DIFF_OFF] = sm[0] / 8388608.0f;
    if (t == 1 && out_size > NU_OFF) out[NU_OFF] = -1.0f;
}

// ---------------------------------------------------------------------------
extern "C" void kernel_launch(void* const* d_in, const int* in_sizes, int n_in,
                              void* d_out, int out_size, void* d_ws, size_t ws_size,
                              hipStream_t stream) {
    const float* input = (const float*)d_in[0];   // [32,64,64,64]
    const float* embed = (const float*)d_in[1];   // [64,1024]
    float* out = (float*)d_out;
    float* ws  = (float*)d_ws;

    float* hee      = ws + WS_HEE;
    float* embedT   = ws + WS_EMBEDT;
    float* partials = ws + WS_PARTIALS;
    float* row_mse  = ws + WS_RMSE;
    int*   counter  = (int*)(ws + WS_COUNTER);
    int*   flaglist = (int*)(ws + WS_FLAGLIST);
    unsigned char* bpk = (unsigned char*)(ws + WS_BPK);

    vq_prep<<<36, 256, 0, stream>>>(embed, embedT, hee, counter, bpk);
    vq_score_mfma<<<1024, 256, 0, stream>>>(input, bpk, embedT,
                                            out, out + IND_OFF, row_mse,
                                            counter, flaglist);
    vq_rescore<<<2048, 64, 0, stream>>>(input, embedT, hee, counter, flaglist,
                                        out, out + IND_OFF, row_mse);
    vq_mse_reduce<<<512, 256, 0, stream>>>(row_mse, partials);
    vq_finalize<<<1, 256, 0, stream>>>(partials, out, out_size);
}